// Round 3
// baseline (1919.962 us; speedup 1.0000x reference)
//
#include <hip/hip_runtime.h>

#define B_   8
#define CD   256
#define WW_  112
#define HW_  12544
#define NH_  4
#define EPS_ 1e-5f

// ---------------- GEMM: Y[b,m,n] = sum_k W[m,k] * X[b,k,n] ----------------
// MODE 0: BN1 + SiLU epilogue   MODE 1: plain   MODE 2: BN2 + residual
template <int MODE>
__global__ __launch_bounds__(256) void gemm_cm(
    const float* __restrict__ Wm,
    const float* __restrict__ X,
    float* __restrict__ Y,
    int M,
    const float* __restrict__ gg,
    const float* __restrict__ bbt,
    const float* __restrict__ mm,
    const float* __restrict__ vv,
    const float* __restrict__ resid)
{
    __shared__ float As[16][64];
    __shared__ float Bs[16][64];
    const int tid = threadIdx.x;
    const int m0 = blockIdx.x * 64;
    const int n0 = blockIdx.y * 64;
    const int b  = blockIdx.z;
    const int ty = tid >> 4, tx = tid & 15;
    const float* Xb = X + (size_t)b * CD * HW_;

    float acc[4][4] = {};

    const int ai = tid >> 2;          // 0..63  (m row in tile)
    const int ak = (tid & 3) * 4;     // 0,4,8,12 (k quad)
    const int bk = tid >> 4;          // 0..15 (k row)
    const int bj = (tid & 15) * 4;    // n quad

    for (int k0 = 0; k0 < CD; k0 += 16) {
        float4 av = *reinterpret_cast<const float4*>(&Wm[(size_t)(m0 + ai) * CD + k0 + ak]);
        float4 bv = *reinterpret_cast<const float4*>(&Xb[(size_t)(k0 + bk) * HW_ + n0 + bj]);
        As[ak + 0][ai] = av.x;
        As[ak + 1][ai] = av.y;
        As[ak + 2][ai] = av.z;
        As[ak + 3][ai] = av.w;
        *reinterpret_cast<float4*>(&Bs[bk][bj]) = bv;
        __syncthreads();
        #pragma unroll
        for (int kk = 0; kk < 16; ++kk) {
            float4 a4 = *reinterpret_cast<const float4*>(&As[kk][ty * 4]);
            float4 b4 = *reinterpret_cast<const float4*>(&Bs[kk][tx * 4]);
            float a[4]  = {a4.x, a4.y, a4.z, a4.w};
            float bq[4] = {b4.x, b4.y, b4.z, b4.w};
            #pragma unroll
            for (int ii = 0; ii < 4; ++ii)
                #pragma unroll
                for (int jj = 0; jj < 4; ++jj)
                    acc[ii][jj] += a[ii] * bq[jj];
        }
        __syncthreads();
    }

    #pragma unroll
    for (int ii = 0; ii < 4; ++ii) {
        const int m = m0 + ty * 4 + ii;
        float sc = 1.f, sh = 0.f;
        if constexpr (MODE != 1) {
            sc = gg[m] * rsqrtf(vv[m] + EPS_);
            sh = bbt[m] - mm[m] * sc;
        }
        float o4[4];
        #pragma unroll
        for (int jj = 0; jj < 4; ++jj) {
            float v = acc[ii][jj];
            if constexpr (MODE == 0) {
                v = v * sc + sh;
                v = v / (1.f + __expf(-v));   // SiLU
            } else if constexpr (MODE == 2) {
                v = v * sc + sh;
            }
            o4[jj] = v;
        }
        const size_t yoff = ((size_t)b * M + m) * HW_ + n0 + tx * 4;
        if constexpr (MODE == 2) {
            const float4 rv = *reinterpret_cast<const float4*>(&resid[yoff]);
            o4[0] += rv.x; o4[1] += rv.y; o4[2] += rv.z; o4[3] += rv.w;
        }
        float4 st = {o4[0], o4[1], o4[2], o4[3]};
        *reinterpret_cast<float4*>(&Y[yoff]) = st;
    }
}

// ---------------- RoPE (in place on q and k of qkv, channel-major) ----------------
__global__ __launch_bounds__(256) void rope_kernel(float* __restrict__ qkv)
{
    const int n = blockIdx.x * 256 + threadIdx.x;   // < HW_
    const int combo = blockIdx.y;                   // qk(1) head(2) blk(1) pair(4)
    const int b = blockIdx.z;
    const int pair = combo & 15;          // dd in 0..15 within 32-block
    const int blk  = (combo >> 4) & 1;    // 0: height rope, 1: width rope
    const int head = (combo >> 5) & 3;
    const int qk   = combo >> 7;          // 0: q, 1: k
    const int h = n / WW_;
    const int w = n - h * WW_;
    const float pos = (blk == 0) ? (float)h : (float)w;
    const float C = 13.28771237954945f / 16.f;  // log2(10000)/16 -> but used with exp2f below
    const float inv_lo = exp2f(-(float)(pair >> 1) * C);
    const float inv_hi = exp2f(-(float)(8 + (pair >> 1)) * C);
    float s_lo, c_lo, s_hi, c_hi;
    __sincosf(pos * inv_lo, &s_lo, &c_lo);
    __sincosf(pos * inv_hi, &s_hi, &c_hi);
    const size_t base = ((size_t)b * 768 + qk * 256 + head * 64 + blk * 32 + pair) * HW_ + n;
    const float t_lo = qkv[base];
    const float t_hi = qkv[base + (size_t)16 * HW_];
    qkv[base]                    = t_lo * c_lo - t_hi * s_lo;
    qkv[base + (size_t)16 * HW_] = t_hi * c_hi + t_lo * s_hi;
}

// ---------------- window attention: 1 wave per (b, head, window) ----------------
__global__ __launch_bounds__(64) void winattn(const float* __restrict__ qkv,
                                              float* __restrict__ lwa)
{
    __shared__ float Ks[49 * 64];
    __shared__ float Vs[49 * 64];
    __shared__ float Ss[49 * 65];
    const int win = blockIdx.x, head = blockIdx.y, b = blockIdx.z;
    const int hb = win >> 4, wb = win & 15;
    const int lane = threadIdx.x;
    const size_t qbase = ((size_t)b * 768 + head * 64) * HW_;
    const size_t kbase = ((size_t)b * 768 + 256 + head * 64) * HW_;
    const size_t vbase = ((size_t)b * 768 + 512 + head * 64) * HW_;
    const int nwbase = (hb * 7) * WW_ + wb * 7;

    for (int idx = lane; idx < 49 * 64; idx += 64) {
        const int d = idx / 49;
        const int i = idx - d * 49;
        const int r = i / 7, c = i - r * 7;
        const int n = nwbase + r * WW_ + c;
        Ks[i * 64 + d] = qkv[kbase + (size_t)d * HW_ + n];
        Vs[i * 64 + d] = qkv[vbase + (size_t)d * HW_ + n];
    }
    __syncthreads();

    const int i = lane;
    if (i < 49) {
        const int r = i / 7, c = i - r * 7;
        const int n = nwbase + r * WW_ + c;
        float q[64];
        #pragma unroll
        for (int d = 0; d < 64; ++d) q[d] = qkv[qbase + (size_t)d * HW_ + n];

        float mx = -1e30f;
        for (int j = 0; j < 49; ++j) {
            float a0 = 0.f, a1 = 0.f, a2 = 0.f, a3 = 0.f;
            #pragma unroll
            for (int d = 0; d < 64; d += 4) {
                a0 += q[d]     * Ks[j * 64 + d];
                a1 += q[d + 1] * Ks[j * 64 + d + 1];
                a2 += q[d + 2] * Ks[j * 64 + d + 2];
                a3 += q[d + 3] * Ks[j * 64 + d + 3];
            }
            const float s = ((a0 + a1) + (a2 + a3)) * 0.125f;  // HD^-0.5
            mx = fmaxf(mx, s);
            Ss[j * 65 + i] = s;
        }
        float sum = 0.f;
        for (int j = 0; j < 49; ++j) {
            const float e = __expf(Ss[j * 65 + i] - mx);
            sum += e;
            Ss[j * 65 + i] = e;
        }
        float o[64];
        #pragma unroll
        for (int d = 0; d < 64; ++d) o[d] = 0.f;
        for (int j = 0; j < 49; ++j) {
            const float p = Ss[j * 65 + i];
            #pragma unroll
            for (int d = 0; d < 64; ++d) o[d] += p * Vs[j * 64 + d];
        }
        const float rs = 1.f / sum;
        const size_t ob = ((size_t)b * 256 + head * 64) * HW_ + n;
        #pragma unroll
        for (int d = 0; d < 64; ++d) lwa[ob + (size_t)d * HW_] = o[d] * rs;
    }
}

// ---------------- linear attention: KV / Ksum reduction ----------------
__global__ __launch_bounds__(256) void kvred(const float* __restrict__ qkv,
                                             float* __restrict__ kvbuf)
{
    __shared__ float K2s[8][64];
    __shared__ float V2s[8][64];
    const int sp = blockIdx.x, head = blockIdx.y, b = blockIdx.z;
    const int tid = threadIdx.x;
    const size_t kbase = ((size_t)b * 768 + 256 + head * 64) * HW_;
    const size_t vbase = ((size_t)b * 768 + 512 + head * 64) * HW_;
    const int n_start = sp * (HW_ / 16);
    const int ki0 = (tid >> 4) * 4;
    const int vi0 = (tid & 15) * 4;
    float acc[4][4] = {};
    float ksm[4] = {0.f, 0.f, 0.f, 0.f};

    for (int t0 = 0; t0 < HW_ / 16; t0 += 8) {
        #pragma unroll
        for (int l = 0; l < 4; ++l) {
            const int idx = l * 256 + tid;
            const int t = idx >> 7;
            const int which = (idx >> 6) & 1;
            const int d = idx & 63;
            const int n = n_start + t0 + t;
            if (which == 0) {
                const float k = qkv[kbase + (size_t)d * HW_ + n];
                K2s[t][d] = k > 0.f ? k + 1.f : __expf(k);   // elu(k)+1
            } else {
                V2s[t][d] = qkv[vbase + (size_t)d * HW_ + n];
            }
        }
        __syncthreads();
        #pragma unroll
        for (int t = 0; t < 8; ++t) {
            float kk[4], vv[4];
            #pragma unroll
            for (int a = 0; a < 4; ++a) { kk[a] = K2s[t][ki0 + a]; vv[a] = V2s[t][vi0 + a]; }
            #pragma unroll
            for (int a = 0; a < 4; ++a)
                #pragma unroll
                for (int c = 0; c < 4; ++c) acc[a][c] += kk[a] * vv[c];
            if (vi0 == 0) {
                #pragma unroll
                for (int a = 0; a < 4; ++a) ksm[a] += kk[a];
            }
        }
        __syncthreads();
    }
    float* dst = kvbuf + (size_t)(b * NH_ + head) * (4096 + 64);
    #pragma unroll
    for (int a = 0; a < 4; ++a)
        #pragma unroll
        for (int c = 0; c < 4; ++c) atomicAdd(&dst[(ki0 + a) * 64 + vi0 + c], acc[a][c]);
    if (vi0 == 0) {
        #pragma unroll
        for (int a = 0; a < 4; ++a) atomicAdd(&dst[4096 + ki0 + a], ksm[a]);
    }
}

// ---------------- linear attention numerator/denominator + gate blend ----------------
__global__ __launch_bounds__(256) void lin_combine(const float* __restrict__ qkv,
                                                   const float* __restrict__ kvbuf,
                                                   const float* __restrict__ gate,
                                                   float* __restrict__ comb)  // in: lwa, out: comb (in place)
{
    const int head = blockIdx.y, b = blockIdx.z;
    const int n = blockIdx.x * 256 + threadIdx.x;
    const float* kv = kvbuf + (size_t)(b * NH_ + head) * (4096 + 64);
    const float* ksum = kv + 4096;
    const size_t qb = ((size_t)b * 768 + head * 64) * HW_ + n;
    float num[64];
    #pragma unroll
    for (int d = 0; d < 64; ++d) num[d] = 0.f;
    float den = 0.f;
    for (int ch = 0; ch < 64; ++ch) {
        const float qv = qkv[qb + (size_t)ch * HW_];
        const float q2 = qv > 0.f ? qv + 1.f : __expf(qv);   // elu(q)+1
        den += q2 * ksum[ch];
        #pragma unroll
        for (int d = 0; d < 64; ++d) num[d] += q2 * kv[ch * 64 + d];
    }
    den += 1e-6f;
    const float g  = 1.f / (1.f + __expf(-gate[0]));
    const float w2 = (1.f - g) / den;
    const size_t ob = ((size_t)b * 256 + head * 64) * HW_ + n;
    #pragma unroll
    for (int d = 0; d < 64; ++d) {
        const float l = comb[ob + (size_t)d * HW_];
        comb[ob + (size_t)d * HW_] = g * l + w2 * num[d];
    }
}

extern "C" void kernel_launch(void* const* d_in, const int* in_sizes, int n_in,
                              void* d_out, int out_size, void* d_ws, size_t ws_size,
                              hipStream_t stream)
{
    (void)in_sizes; (void)n_in; (void)out_size;
    const float* x     = (const float*)d_in[0];
    const float* w_in  = (const float*)d_in[1];
    const float* bn1g  = (const float*)d_in[2];
    const float* bn1b  = (const float*)d_in[3];
    const float* bn1m  = (const float*)d_in[4];
    const float* bn1v  = (const float*)d_in[5];
    const float* w_qkv = (const float*)d_in[6];
    const float* w_out = (const float*)d_in[7];
    const float* bn2g  = (const float*)d_in[8];
    const float* bn2b  = (const float*)d_in[9];
    const float* bn2m  = (const float*)d_in[10];
    const float* bn2v  = (const float*)d_in[11];
    const float* gate  = (const float*)d_in[12];
    float* out = (float*)d_out;
    float* ws  = (float*)d_ws;

    // Adaptive batch chunking to fit ws_size.
    // Layout: [kvbf: 8*4*(4096+64) floats] [xp: nb*256*HW] [qkv: nb*768*HW]
    const size_t kv_floats   = (size_t)B_ * NH_ * (4096 + 64);
    const size_t per_batch_f = (size_t)(CD + 768) * HW_;     // xp + qkv floats per batch
    const size_t avail_f     = ws_size / sizeof(float);
    int nb = 1;
    if (avail_f > kv_floats + per_batch_f) {
        size_t fit = (avail_f - kv_floats) / per_batch_f;
        nb = (int)(fit < 8 ? fit : 8);
        if (nb < 1) nb = 1;
    }

    float* kvbf = ws;
    float* xp   = ws + kv_floats;                      // nb*256*HW; reused as lwa/comb
    float* qkv  = xp + (size_t)nb * CD * HW_;          // nb*768*HW

    for (int b0 = 0; b0 < B_; b0 += nb) {
        const int cb = (B_ - b0) < nb ? (B_ - b0) : nb;
        const float* xc  = x   + (size_t)b0 * CD * HW_;
        float*       oc  = out + (size_t)b0 * CD * HW_;

        // 1) in-proj + BN1 + SiLU
        gemm_cm<0><<<dim3(4, 196, cb), 256, 0, stream>>>(w_in, xc, xp, 256, bn1g, bn1b, bn1m, bn1v, nullptr);
        // 2) qkv projection
        gemm_cm<1><<<dim3(12, 196, cb), 256, 0, stream>>>(w_qkv, xp, qkv, 768, nullptr, nullptr, nullptr, nullptr, nullptr);
        // 3) RoPE on q, k (in place)
        rope_kernel<<<dim3(49, 256, cb), 256, 0, stream>>>(qkv);
        // 4) local window attention -> lwa (into xp region, xp is dead now)
        winattn<<<dim3(256, 4, cb), 64, 0, stream>>>(qkv, xp);
        // 5) linear attention KV reduction
        hipMemsetAsync(kvbf, 0, (size_t)cb * NH_ * (4096 + 64) * sizeof(float), stream);
        kvred<<<dim3(16, 4, cb), 256, 0, stream>>>(qkv, kvbf);
        // 6) linear attention + gate blend (in place over lwa)
        lin_combine<<<dim3(49, 4, cb), 256, 0, stream>>>(qkv, kvbf, gate, xp);
        // 7) out-proj + BN2 + residual
        gemm_cm<2><<<dim3(4, 196, cb), 256, 0, stream>>>(w_out, xp, out + (size_t)b0 * CD * HW_, 256, bn2g, bn2b, bn2m, bn2v, xc);
        (void)oc;
    }
}

// Round 4
// 1284.015 us; speedup vs baseline: 1.4953x; 1.4953x over previous
//
#include <hip/hip_runtime.h>

#define B_   8
#define CD   256
#define WW_  112
#define HW_  12544
#define NH_  4
#define EPS_ 1e-5f
#define C16_ 0.83048202372184059f   // log2(10000)/16

typedef __bf16 bf16;
typedef __bf16 bf16x8 __attribute__((ext_vector_type(8)));
typedef __bf16 bf16x4 __attribute__((ext_vector_type(4)));
typedef float  f32x4  __attribute__((ext_vector_type(4)));

// ---------------- pack weights fp32 -> bf16 ----------------
__global__ __launch_bounds__(256) void pack_w(const float* __restrict__ w_in,
                                              const float* __restrict__ w_qkv,
                                              const float* __restrict__ w_out,
                                              bf16* __restrict__ wb)
{
    const int which = blockIdx.y;
    const float* src = which == 0 ? w_in : (which == 1 ? w_qkv : w_out);
    const int sz = (which == 1) ? 196608 : 65536;
    bf16* dst = wb + (which == 0 ? 0 : (which == 1 ? 65536 : 262144));
    const int i = (blockIdx.x * 256 + threadIdx.x) * 4;
    if (i < sz) {
        float4 v = *reinterpret_cast<const float4*>(&src[i]);
        bf16x4 o;
        o[0] = (bf16)v.x; o[1] = (bf16)v.y; o[2] = (bf16)v.z; o[3] = (bf16)v.w;
        *reinterpret_cast<bf16x4*>(&dst[i]) = o;
    }
}

// ---------------- pack + transpose x: [b][c][hw] f32 -> [b][hw][c] bf16 ----------------
__global__ __launch_bounds__(256) void pack_x(const float* __restrict__ x,
                                              bf16* __restrict__ xb)
{
    __shared__ float tile[32][33];
    const int hw0 = blockIdx.x * 32, c0 = blockIdx.y * 32, b = blockIdx.z;
    const int t = threadIdx.x;
    {
        const int cl = t >> 3, h4 = (t & 7) * 4;
        float4 v = *reinterpret_cast<const float4*>(&x[((size_t)b * CD + c0 + cl) * HW_ + hw0 + h4]);
        tile[cl][h4 + 0] = v.x; tile[cl][h4 + 1] = v.y;
        tile[cl][h4 + 2] = v.z; tile[cl][h4 + 3] = v.w;
    }
    __syncthreads();
    {
        const int hl = t >> 3, c4 = (t & 7) * 4;
        bf16x4 o;
        #pragma unroll
        for (int j = 0; j < 4; ++j) o[j] = (bf16)tile[c4 + j][hl];
        *reinterpret_cast<bf16x4*>(&xb[((size_t)b * HW_ + hw0 + hl) * CD + c0 + c4]) = o;
    }
}

// ---------------- MFMA GEMM: Y[m,n] = sum_k W[m,k] X[n,k]  (X token-major) ----------------
// MODE 0: BN1+SiLU -> bf16 token-major.  MODE 1: rope(m<512) -> bf16 token-major.
// MODE 2: BN2 + residual -> fp32 channel-major.
template <int MODE, int MT>
__global__ __launch_bounds__(256) void mfma_gemm(
    const bf16* __restrict__ Wb,      // [MT][256]
    const bf16* __restrict__ Xtm,     // [cb][HW][256]
    bf16* __restrict__ Ytm,           // MODE 0/1
    float* __restrict__ Yf,           // MODE 2
    const float* __restrict__ gg, const float* __restrict__ bbt,
    const float* __restrict__ mm, const float* __restrict__ vv,
    const float* __restrict__ resid)  // MODE 2
{
    __shared__ bf16 Al[128][40];      // +8 pad: 2-way-max bank aliasing
    __shared__ bf16 Bl[128][40];
    __shared__ float scL[128], shL[128];

    const int tid = threadIdx.x;
    const int m0 = blockIdx.x * 128;
    const int n0 = blockIdx.y * 128;
    const int bz = blockIdx.z;
    const int lane = tid & 63;
    const int wid  = tid >> 6;
    const int lr = lane & 15;          // frag row/col within 16
    const int lg = lane >> 4;          // k-octet / row-quad selector
    const int wmL = (wid >> 1) * 64;
    const int wnL = (wid & 1) * 64;

    if constexpr (MODE != 1) {
        if (tid < 128) {
            const int m = m0 + tid;
            const float sc = gg[m] * rsqrtf(vv[m] + EPS_);
            scL[tid] = sc;
            shL[tid] = bbt[m] - mm[m] * sc;
        }
    }

    f32x4 acc[4][4];
    #pragma unroll
    for (int a = 0; a < 4; ++a)
        #pragma unroll
        for (int c = 0; c < 4; ++c) acc[a][c] = (f32x4){0.f, 0.f, 0.f, 0.f};

    const int srow = tid >> 1;
    const int skh  = (tid & 1) * 16;
    const bf16* gA = Wb + (size_t)(m0 + srow) * 256 + skh;
    const bf16* gB = Xtm + ((size_t)bz * HW_ + n0 + srow) * 256 + skh;

    for (int k0 = 0; k0 < 256; k0 += 32) {
        bf16x8 a0 = *reinterpret_cast<const bf16x8*>(gA + k0);
        bf16x8 a1 = *reinterpret_cast<const bf16x8*>(gA + k0 + 8);
        bf16x8 b0 = *reinterpret_cast<const bf16x8*>(gB + k0);
        bf16x8 b1 = *reinterpret_cast<const bf16x8*>(gB + k0 + 8);
        __syncthreads();
        *reinterpret_cast<bf16x8*>(&Al[srow][skh])     = a0;
        *reinterpret_cast<bf16x8*>(&Al[srow][skh + 8]) = a1;
        *reinterpret_cast<bf16x8*>(&Bl[srow][skh])     = b0;
        *reinterpret_cast<bf16x8*>(&Bl[srow][skh + 8]) = b1;
        __syncthreads();
        bf16x8 af[4], bfr[4];
        #pragma unroll
        for (int f = 0; f < 4; ++f) {
            af[f]  = *reinterpret_cast<const bf16x8*>(&Al[wmL + f * 16 + lr][lg * 8]);
            bfr[f] = *reinterpret_cast<const bf16x8*>(&Bl[wnL + f * 16 + lr][lg * 8]);
        }
        #pragma unroll
        for (int fm = 0; fm < 4; ++fm)
            #pragma unroll
            for (int fn = 0; fn < 4; ++fn)
                acc[fm][fn] = __builtin_amdgcn_mfma_f32_16x16x32_bf16(af[fm], bfr[fn], acc[fm][fn], 0, 0, 0);
    }

    if constexpr (MODE == 1) {
        // RoPE on q,k rows (m < 512). Pair c <-> c+16 lives in frag pairs (0,1),(2,3).
        if (m0 + wmL < 512) {
            #pragma unroll
            for (int fn = 0; fn < 4; ++fn) {
                const int n = n0 + wnL + fn * 16 + lr;
                const int h = n / WW_;
                const int w = n - h * WW_;
                #pragma unroll
                for (int pb = 0; pb < 4; pb += 2) {
                    const float pos = (pb == 0) ? (float)h : (float)w;
                    #pragma unroll
                    for (int i = 0; i < 4; ++i) {
                        const int r = lg * 4 + i;        // 0..15
                        const int idx = r >> 1;          // 0..7
                        const float ilo = exp2f(-(float)idx * C16_);
                        const float ihi = exp2f(-(float)(idx + 8) * C16_);
                        float slo, clo, shi, chi;
                        __sincosf(pos * ilo, &slo, &clo);
                        __sincosf(pos * ihi, &shi, &chi);
                        const float lo = acc[pb][fn][i], hi = acc[pb + 1][fn][i];
                        acc[pb][fn][i]     = lo * clo - hi * slo;
                        acc[pb + 1][fn][i] = hi * chi + lo * shi;
                    }
                }
            }
        }
    }

    if constexpr (MODE == 2) {
        #pragma unroll
        for (int fm = 0; fm < 4; ++fm)
            #pragma unroll
            for (int i = 0; i < 4; ++i) {
                const int mL = wmL + fm * 16 + lg * 4 + i;
                const float sc = scL[mL], sh = shL[mL];
                const size_t rowoff = ((size_t)bz * CD + m0 + mL) * HW_;
                #pragma unroll
                for (int fn = 0; fn < 4; ++fn) {
                    const int n = n0 + wnL + fn * 16 + lr;
                    Yf[rowoff + n] = acc[fm][fn][i] * sc + sh + resid[rowoff + n];
                }
            }
    } else {
        #pragma unroll
        for (int fm = 0; fm < 4; ++fm) {
            const int mb = m0 + wmL + fm * 16 + lg * 4;
            #pragma unroll
            for (int fn = 0; fn < 4; ++fn) {
                const int n = n0 + wnL + fn * 16 + lr;
                bf16x4 st;
                #pragma unroll
                for (int i = 0; i < 4; ++i) {
                    float v = acc[fm][fn][i];
                    if constexpr (MODE == 0) {
                        const int mL = wmL + fm * 16 + lg * 4 + i;
                        v = v * scL[mL] + shL[mL];
                        v = v / (1.f + __expf(-v));      // SiLU
                    }
                    st[i] = (bf16)v;
                }
                *reinterpret_cast<bf16x4*>(&Ytm[((size_t)bz * HW_ + n) * MT + mb]) = st;
            }
        }
    }
}

// ---------------- linear attention: KV / Ksum reduction (token-major bf16 in) ----------------
__global__ __launch_bounds__(256) void kvred(const bf16* __restrict__ qkvb,
                                             float* __restrict__ kvbuf)
{
    __shared__ float K2s[8][64];
    __shared__ float V2s[8][64];
    const int sp = blockIdx.x, head = blockIdx.y, b = blockIdx.z;
    const int tid = threadIdx.x;
    const int n_start = sp * (HW_ / 16);
    const int ki0 = (tid >> 4) * 4;
    const int vi0 = (tid & 15) * 4;
    float acc[4][4] = {};
    float ksm[4] = {0.f, 0.f, 0.f, 0.f};

    const int which = tid >> 7;          // 0: k, 1: v
    const int jt    = (tid >> 4) & 7;    // token in group
    const int d4    = (tid & 15) * 4;

    for (int t0 = 0; t0 < HW_ / 16; t0 += 8) {
        {
            const int n = n_start + t0 + jt;
            const size_t base = ((size_t)b * HW_ + n) * 768 + 256 + which * 256 + head * 64 + d4;
            bf16x4 v4 = *reinterpret_cast<const bf16x4*>(&qkvb[base]);
            if (which == 0) {
                #pragma unroll
                for (int a = 0; a < 4; ++a) {
                    const float k = (float)v4[a];
                    K2s[jt][d4 + a] = k > 0.f ? k + 1.f : __expf(k);   // elu(k)+1
                }
            } else {
                #pragma unroll
                for (int a = 0; a < 4; ++a) V2s[jt][d4 + a] = (float)v4[a];
            }
        }
        __syncthreads();
        #pragma unroll
        for (int t = 0; t < 8; ++t) {
            float kk[4], vvv[4];
            #pragma unroll
            for (int a = 0; a < 4; ++a) { kk[a] = K2s[t][ki0 + a]; vvv[a] = V2s[t][vi0 + a]; }
            #pragma unroll
            for (int a = 0; a < 4; ++a)
                #pragma unroll
                for (int c = 0; c < 4; ++c) acc[a][c] += kk[a] * vvv[c];
            if (vi0 == 0) {
                #pragma unroll
                for (int a = 0; a < 4; ++a) ksm[a] += kk[a];
            }
        }
        __syncthreads();
    }
    float* dst = kvbuf + (size_t)(b * NH_ + head) * 4160;
    #pragma unroll
    for (int a = 0; a < 4; ++a)
        #pragma unroll
        for (int c = 0; c < 4; ++c) atomicAdd(&dst[(ki0 + a) * 64 + vi0 + c], acc[a][c]);
    if (vi0 == 0) {
        #pragma unroll
        for (int a = 0; a < 4; ++a) atomicAdd(&dst[4096 + ki0 + a], ksm[a]);
    }
}

// ---------------- window attention + linear attention + gate blend ----------------
__global__ __launch_bounds__(64) void winattn_lin(const bf16* __restrict__ qkvb,
                                                  const float* __restrict__ kvbuf,
                                                  const float* __restrict__ gate,
                                                  bf16* __restrict__ combb)
{
    __shared__ float Ks[49 * 64];   // reused as Q2s[d*49+i] after the score phase
    __shared__ float Vs[49 * 64];
    __shared__ float Ss[49 * 65];
    const int win = blockIdx.x, head = blockIdx.y, b = blockIdx.z;
    const int hb = win >> 4, wb = win & 15;
    const int lane = threadIdx.x;
    const int nwbase = hb * 7 * WW_ + wb * 7;

    for (int idx = lane; idx < 392; idx += 64) {     // 49 tokens x 8 ch-octets
        const int j = idx >> 3, d8 = (idx & 7) * 8;
        const int n = nwbase + (j / 7) * WW_ + (j % 7);
        const bf16* pk = qkvb + ((size_t)b * HW_ + n) * 768 + 256 + head * 64 + d8;
        bf16x8 k8 = *reinterpret_cast<const bf16x8*>(pk);
        bf16x8 v8 = *reinterpret_cast<const bf16x8*>(pk + 256);
        #pragma unroll
        for (int e = 0; e < 8; ++e) {
            Ks[j * 64 + d8 + e] = (float)k8[e];
            Vs[j * 64 + d8 + e] = (float)v8[e];
        }
    }

    float q[64];
    int ni = 0;
    if (lane < 49) {
        ni = nwbase + (lane / 7) * WW_ + (lane % 7);
        const bf16* pq = qkvb + ((size_t)b * HW_ + ni) * 768 + head * 64;
        #pragma unroll
        for (int c8 = 0; c8 < 8; ++c8) {
            bf16x8 q8 = *reinterpret_cast<const bf16x8*>(pq + c8 * 8);
            #pragma unroll
            for (int e = 0; e < 8; ++e) q[c8 * 8 + e] = (float)q8[e];
        }
    }
    __syncthreads();

    if (lane < 49) {
        const int i = lane;
        float mx = -1e30f;
        for (int j = 0; j < 49; ++j) {
            float a0 = 0.f, a1 = 0.f, a2 = 0.f, a3 = 0.f;
            #pragma unroll
            for (int d = 0; d < 64; d += 4) {
                a0 += q[d]     * Ks[j * 64 + d];
                a1 += q[d + 1] * Ks[j * 64 + d + 1];
                a2 += q[d + 2] * Ks[j * 64 + d + 2];
                a3 += q[d + 3] * Ks[j * 64 + d + 3];
            }
            const float s = ((a0 + a1) + (a2 + a3)) * 0.125f;
            mx = fmaxf(mx, s);
            Ss[j * 65 + i] = s;
        }
        float sum = 0.f;
        for (int j = 0; j < 49; ++j) {
            const float e = __expf(Ss[j * 65 + i] - mx);
            sum += e;
            Ss[j * 65 + i] = e;
        }
        // ---- linear attention (q is the roped q; wave-synchronous so Ks reuse is safe) ----
        const float g = 1.f / (1.f + __expf(-gate[0]));
        const float* kv   = kvbuf + (size_t)(b * NH_ + head) * 4160;
        const float* ksum = kv + 4096;
        float den = 1e-6f;
        #pragma unroll
        for (int d = 0; d < 64; ++d) {
            float qv = q[d];
            qv = qv > 0.f ? qv + 1.f : __expf(qv);     // elu(q)+1
            den += qv * ksum[d];
            Ks[d * 49 + i] = qv;                        // Q2 spill (static-index safe)
        }
        float o[64];
        #pragma unroll
        for (int d = 0; d < 64; ++d) o[d] = 0.f;
        for (int d = 0; d < 64; ++d) {
            const float q2 = Ks[d * 49 + i];
            #pragma unroll
            for (int dd = 0; dd < 64; ++dd) o[dd] += q2 * kv[d * 64 + dd];
        }
        const float w2 = (1.f - g) / den;
        #pragma unroll
        for (int dd = 0; dd < 64; ++dd) o[dd] *= w2;
        const float grs = g / sum;
        for (int j = 0; j < 49; ++j) {
            const float p = Ss[j * 65 + i] * grs;
            #pragma unroll
            for (int d = 0; d < 64; ++d) o[d] += p * Vs[j * 64 + d];
        }
        bf16* po = combb + ((size_t)b * HW_ + ni) * CD + head * 64;
        #pragma unroll
        for (int d4 = 0; d4 < 16; ++d4) {
            bf16x4 st;
            #pragma unroll
            for (int e = 0; e < 4; ++e) st[e] = (bf16)o[d4 * 4 + e];
            *reinterpret_cast<bf16x4*>(&po[d4 * 4]) = st;
        }
    }
}

extern "C" void kernel_launch(void* const* d_in, const int* in_sizes, int n_in,
                              void* d_out, int out_size, void* d_ws, size_t ws_size,
                              hipStream_t stream)
{
    (void)in_sizes; (void)n_in; (void)out_size;
    const float* x     = (const float*)d_in[0];
    const float* w_in  = (const float*)d_in[1];
    const float* bn1g  = (const float*)d_in[2];
    const float* bn1b  = (const float*)d_in[3];
    const float* bn1m  = (const float*)d_in[4];
    const float* bn1v  = (const float*)d_in[5];
    const float* w_qkv = (const float*)d_in[6];
    const float* w_out = (const float*)d_in[7];
    const float* bn2g  = (const float*)d_in[8];
    const float* bn2b  = (const float*)d_in[9];
    const float* bn2m  = (const float*)d_in[10];
    const float* bn2v  = (const float*)d_in[11];
    const float* gate  = (const float*)d_in[12];
    float* out = (float*)d_out;
    char* base = (char*)d_ws;

    // Fixed region: packed weights (655360 B) + kvbuf (532480 B)
    bf16*  wb  = (bf16*)base;
    float* kvb = (float*)(base + 655360);
    char*  dyn = base + 655360 + 532480;

    const size_t xb_b  = (size_t)HW_ * CD * 2;        // 6,422,528 B per batch
    const size_t qkv_b = (size_t)HW_ * 768 * 2;       // 19,267,584 B per batch
    const size_t per_b = xb_b * 2 + qkv_b;            // xb + xpb + qkv
    size_t avail = ws_size > (size_t)(655360 + 532480) ? ws_size - 655360 - 532480 : 0;
    int nb = (int)(avail / per_b);
    if (nb < 1) nb = 1;
    if (nb > B_) nb = B_;

    bf16* xb  = (bf16*)dyn;
    bf16* xpb = (bf16*)(dyn + (size_t)nb * xb_b);     // reused as combb
    bf16* qkv = (bf16*)(dyn + (size_t)nb * xb_b * 2);

    pack_w<<<dim3(192, 3), 256, 0, stream>>>(w_in, w_qkv, w_out, wb);

    for (int b0 = 0; b0 < B_; b0 += nb) {
        const int cb = (B_ - b0) < nb ? (B_ - b0) : nb;
        const float* xc = x   + (size_t)b0 * CD * HW_;
        float*       oc = out + (size_t)b0 * CD * HW_;

        // 0) transpose+cast x -> token-major bf16
        pack_x<<<dim3(392, 8, cb), 256, 0, stream>>>(xc, xb);
        // 1) in-proj + BN1 + SiLU
        mfma_gemm<0, 256><<<dim3(2, 98, cb), 256, 0, stream>>>(
            wb, xb, xpb, nullptr, bn1g, bn1b, bn1m, bn1v, nullptr);
        // 2) qkv projection + fused RoPE
        mfma_gemm<1, 768><<<dim3(6, 98, cb), 256, 0, stream>>>(
            wb + 65536, xpb, qkv, nullptr, nullptr, nullptr, nullptr, nullptr, nullptr);
        // 3) linear attention KV reduction
        hipMemsetAsync(kvb, 0, (size_t)cb * NH_ * 4160 * sizeof(float), stream);
        kvred<<<dim3(16, 4, cb), 256, 0, stream>>>(qkv, kvb);
        // 4) window attention + linear attention + gate blend -> combb (reuses xpb)
        winattn_lin<<<dim3(256, 4, cb), 64, 0, stream>>>(qkv, kvb, gate, xpb);
        // 5) out-proj + BN2 + residual
        mfma_gemm<2, 256><<<dim3(2, 98, cb), 256, 0, stream>>>(
            wb + 262144, xpb, nullptr, oc, bn2g, bn2b, bn2m, bn2v, xc);
    }
}

// Round 5
// 618.129 us; speedup vs baseline: 3.1061x; 2.0773x over previous
//
#include <hip/hip_runtime.h>

#define B_   8
#define CD   256
#define WW_  112
#define HW_  12544
#define NH_  4
#define EPS_ 1e-5f
#define C16_ 0.83048202372184059f   // log2(10000)/16

typedef __bf16 bf16;
typedef __bf16 bf16x8 __attribute__((ext_vector_type(8)));
typedef __bf16 bf16x4 __attribute__((ext_vector_type(4)));
typedef float  f32x4  __attribute__((ext_vector_type(4)));

// ---------------- pack weights fp32 -> bf16 ----------------
__global__ __launch_bounds__(256) void pack_w(const float* __restrict__ w_in,
                                              const float* __restrict__ w_qkv,
                                              const float* __restrict__ w_out,
                                              bf16* __restrict__ wb)
{
    const int which = blockIdx.y;
    const float* src = which == 0 ? w_in : (which == 1 ? w_qkv : w_out);
    const int sz = (which == 1) ? 196608 : 65536;
    bf16* dst = wb + (which == 0 ? 0 : (which == 1 ? 65536 : 262144));
    const int i = (blockIdx.x * 256 + threadIdx.x) * 4;
    if (i < sz) {
        float4 v = *reinterpret_cast<const float4*>(&src[i]);
        bf16x4 o;
        o[0] = (bf16)v.x; o[1] = (bf16)v.y; o[2] = (bf16)v.z; o[3] = (bf16)v.w;
        *reinterpret_cast<bf16x4*>(&dst[i]) = o;
    }
}

// ---------------- pack + transpose x: [b][c][hw] f32 -> [b][hw][c] bf16 ----------------
__global__ __launch_bounds__(256) void pack_x(const float* __restrict__ x,
                                              bf16* __restrict__ xb)
{
    __shared__ float tile[32][33];
    const int hw0 = blockIdx.x * 32, c0 = blockIdx.y * 32, b = blockIdx.z;
    const int t = threadIdx.x;
    {
        const int cl = t >> 3, h4 = (t & 7) * 4;
        float4 v = *reinterpret_cast<const float4*>(&x[((size_t)b * CD + c0 + cl) * HW_ + hw0 + h4]);
        tile[cl][h4 + 0] = v.x; tile[cl][h4 + 1] = v.y;
        tile[cl][h4 + 2] = v.z; tile[cl][h4 + 3] = v.w;
    }
    __syncthreads();
    {
        const int hl = t >> 3, c4 = (t & 7) * 4;
        bf16x4 o;
        #pragma unroll
        for (int j = 0; j < 4; ++j) o[j] = (bf16)tile[c4 + j][hl];
        *reinterpret_cast<bf16x4*>(&xb[((size_t)b * HW_ + hw0 + hl) * CD + c0 + c4]) = o;
    }
}

// ---------------- MFMA GEMM: Y[m,n] = sum_k W[m,k] X[n,k]  (X token-major) ----------------
// MODE 0: BN1+SiLU -> bf16 token-major.  MODE 1: rope(m<512) -> bf16 token-major.
// MODE 2: BN2 + residual -> fp32 channel-major.
template <int MODE, int MT>
__global__ __launch_bounds__(256) void mfma_gemm(
    const bf16* __restrict__ Wb,      // [MT][256]
    const bf16* __restrict__ Xtm,     // [cb][HW][256]
    bf16* __restrict__ Ytm,           // MODE 0/1
    float* __restrict__ Yf,           // MODE 2
    const float* __restrict__ gg, const float* __restrict__ bbt,
    const float* __restrict__ mm, const float* __restrict__ vv,
    const float* __restrict__ resid)  // MODE 2
{
    __shared__ bf16 Al[128][40];      // +8 pad
    __shared__ bf16 Bl[128][40];
    __shared__ float scL[128], shL[128];

    const int tid = threadIdx.x;
    const int m0 = blockIdx.x * 128;
    const int n0 = blockIdx.y * 128;
    const int bz = blockIdx.z;
    const int lane = tid & 63;
    const int wid  = tid >> 6;
    const int lr = lane & 15;
    const int lg = lane >> 4;
    const int wmL = (wid >> 1) * 64;
    const int wnL = (wid & 1) * 64;

    if constexpr (MODE != 1) {
        if (tid < 128) {
            const int m = m0 + tid;
            const float sc = gg[m] * rsqrtf(vv[m] + EPS_);
            scL[tid] = sc;
            shL[tid] = bbt[m] - mm[m] * sc;
        }
    }

    f32x4 acc[4][4];
    #pragma unroll
    for (int a = 0; a < 4; ++a)
        #pragma unroll
        for (int c = 0; c < 4; ++c) acc[a][c] = (f32x4){0.f, 0.f, 0.f, 0.f};

    const int srow = tid >> 1;
    const int skh  = (tid & 1) * 16;
    const bf16* gA = Wb + (size_t)(m0 + srow) * 256 + skh;
    const bf16* gB = Xtm + ((size_t)bz * HW_ + n0 + srow) * 256 + skh;

    for (int k0 = 0; k0 < 256; k0 += 32) {
        bf16x8 a0 = *reinterpret_cast<const bf16x8*>(gA + k0);
        bf16x8 a1 = *reinterpret_cast<const bf16x8*>(gA + k0 + 8);
        bf16x8 b0 = *reinterpret_cast<const bf16x8*>(gB + k0);
        bf16x8 b1 = *reinterpret_cast<const bf16x8*>(gB + k0 + 8);
        __syncthreads();
        *reinterpret_cast<bf16x8*>(&Al[srow][skh])     = a0;
        *reinterpret_cast<bf16x8*>(&Al[srow][skh + 8]) = a1;
        *reinterpret_cast<bf16x8*>(&Bl[srow][skh])     = b0;
        *reinterpret_cast<bf16x8*>(&Bl[srow][skh + 8]) = b1;
        __syncthreads();
        bf16x8 af[4], bfr[4];
        #pragma unroll
        for (int f = 0; f < 4; ++f) {
            af[f]  = *reinterpret_cast<const bf16x8*>(&Al[wmL + f * 16 + lr][lg * 8]);
            bfr[f] = *reinterpret_cast<const bf16x8*>(&Bl[wnL + f * 16 + lr][lg * 8]);
        }
        #pragma unroll
        for (int fm = 0; fm < 4; ++fm)
            #pragma unroll
            for (int fn = 0; fn < 4; ++fn)
                acc[fm][fn] = __builtin_amdgcn_mfma_f32_16x16x32_bf16(af[fm], bfr[fn], acc[fm][fn], 0, 0, 0);
    }

    if constexpr (MODE == 1) {
        if (m0 + wmL < 512) {
            #pragma unroll
            for (int fn = 0; fn < 4; ++fn) {
                const int n = n0 + wnL + fn * 16 + lr;
                const int h = n / WW_;
                const int w = n - h * WW_;
                #pragma unroll
                for (int pb = 0; pb < 4; pb += 2) {
                    const float pos = (pb == 0) ? (float)h : (float)w;
                    #pragma unroll
                    for (int i = 0; i < 4; ++i) {
                        const int r = lg * 4 + i;
                        const int idx = r >> 1;
                        const float ilo = exp2f(-(float)idx * C16_);
                        const float ihi = exp2f(-(float)(idx + 8) * C16_);
                        float slo, clo, shi, chi;
                        __sincosf(pos * ilo, &slo, &clo);
                        __sincosf(pos * ihi, &shi, &chi);
                        const float lo = acc[pb][fn][i], hi = acc[pb + 1][fn][i];
                        acc[pb][fn][i]     = lo * clo - hi * slo;
                        acc[pb + 1][fn][i] = hi * chi + lo * shi;
                    }
                }
            }
        }
    }

    if constexpr (MODE == 2) {
        #pragma unroll
        for (int fm = 0; fm < 4; ++fm)
            #pragma unroll
            for (int i = 0; i < 4; ++i) {
                const int mL = wmL + fm * 16 + lg * 4 + i;
                const float sc = scL[mL], sh = shL[mL];
                const size_t rowoff = ((size_t)bz * CD + m0 + mL) * HW_;
                #pragma unroll
                for (int fn = 0; fn < 4; ++fn) {
                    const int n = n0 + wnL + fn * 16 + lr;
                    Yf[rowoff + n] = acc[fm][fn][i] * sc + sh + resid[rowoff + n];
                }
            }
    } else {
        #pragma unroll
        for (int fm = 0; fm < 4; ++fm) {
            const int mb = m0 + wmL + fm * 16 + lg * 4;
            #pragma unroll
            for (int fn = 0; fn < 4; ++fn) {
                const int n = n0 + wnL + fn * 16 + lr;
                bf16x4 st;
                #pragma unroll
                for (int i = 0; i < 4; ++i) {
                    float v = acc[fm][fn][i];
                    if constexpr (MODE == 0) {
                        const int mL = wmL + fm * 16 + lg * 4 + i;
                        v = v * scL[mL] + shL[mL];
                        v = v / (1.f + __expf(-v));      // SiLU
                    }
                    st[i] = (bf16)v;
                }
                *reinterpret_cast<bf16x4*>(&Ytm[((size_t)bz * HW_ + n) * MT + mb]) = st;
            }
        }
    }
}

// ---------------- linear attention: KV^T / Ksum reduction (token-major bf16 in) ----------------
// Stores KVt[d][c] = sum_s elu1(K[s][c]) * V[s][d]   (transposed for MFMA A-operand use)
__global__ __launch_bounds__(256) void kvred(const bf16* __restrict__ qkvb,
                                             float* __restrict__ kvbuf)
{
    __shared__ float K2s[8][64];
    __shared__ float V2s[8][64];
    const int sp = blockIdx.x, head = blockIdx.y, b = blockIdx.z;
    const int tid = threadIdx.x;
    const int n_start = sp * (HW_ / 16);
    const int ki0 = (tid >> 4) * 4;
    const int vi0 = (tid & 15) * 4;
    float acc[4][4] = {};
    float ksm[4] = {0.f, 0.f, 0.f, 0.f};

    const int which = tid >> 7;          // 0: k, 1: v
    const int jt    = (tid >> 4) & 7;    // token in group
    const int d4    = (tid & 15) * 4;

    for (int t0 = 0; t0 < HW_ / 16; t0 += 8) {
        {
            const int n = n_start + t0 + jt;
            const size_t base = ((size_t)b * HW_ + n) * 768 + 256 + which * 256 + head * 64 + d4;
            bf16x4 v4 = *reinterpret_cast<const bf16x4*>(&qkvb[base]);
            if (which == 0) {
                #pragma unroll
                for (int a = 0; a < 4; ++a) {
                    const float k = (float)v4[a];
                    K2s[jt][d4 + a] = k > 0.f ? k + 1.f : __expf(k);   // elu(k)+1
                }
            } else {
                #pragma unroll
                for (int a = 0; a < 4; ++a) V2s[jt][d4 + a] = (float)v4[a];
            }
        }
        __syncthreads();
        #pragma unroll
        for (int t = 0; t < 8; ++t) {
            float kk[4], vvv[4];
            #pragma unroll
            for (int a = 0; a < 4; ++a) { kk[a] = K2s[t][ki0 + a]; vvv[a] = V2s[t][vi0 + a]; }
            #pragma unroll
            for (int a = 0; a < 4; ++a)
                #pragma unroll
                for (int c = 0; c < 4; ++c) acc[a][c] += kk[a] * vvv[c];
            if (vi0 == 0) {
                #pragma unroll
                for (int a = 0; a < 4; ++a) ksm[a] += kk[a];
            }
        }
        __syncthreads();
    }
    float* dst = kvbuf + (size_t)(b * NH_ + head) * 4160;
    #pragma unroll
    for (int a = 0; a < 4; ++a)
        #pragma unroll
        for (int c = 0; c < 4; ++c) atomicAdd(&dst[(vi0 + c) * 64 + ki0 + a], acc[a][c]);  // transposed
    if (vi0 == 0) {
        #pragma unroll
        for (int a = 0; a < 4; ++a) atomicAdd(&dst[4096 + ki0 + a], ksm[a]);
    }
}

// ---------------- MFMA window attention + linear attention + gate blend ----------------
// One wave per (window, head, b). S^T = mfma(K,Q); softmax via 2x shfl_xor;
// acc = mfma(KVt, Q2*w2) + mfma(Vt, Pt). 96 MFMAs total.
__global__ __launch_bounds__(64) void winattn_mfma(
    const bf16* __restrict__ qkvb, const float* __restrict__ kvbuf,
    const float* __restrict__ gate, bf16* __restrict__ combb)
{
    __shared__ bf16 Pl[64][72];       // P^T col-major: Pl[q][j], padded
    const int win = blockIdx.x, head = blockIdx.y, b = blockIdx.z;
    const int lane = threadIdx.x;
    const int lr = lane & 15, lg = lane >> 4;
    const int nwbase = (win >> 4) * 7 * WW_ + (win & 15) * 7;
    const size_t tb = (size_t)b * HW_;
    const int ch = lg * 8;            // k-slice base channel

    // token index for window-local t (clamped to 48): n = base + (t/7)*112 + t%7
    #define TOK(t_) ({ int tt_ = (t_) > 48 ? 48 : (t_); int rr_ = (tt_ * 9363) >> 16; nwbase + rr_ * WW_ + (tt_ - rr_ * 7); })

    // ---- load Q (B-operand) and K (A-operand) frags: token = f*16+lr, k = ch+32*k0+e ----
    bf16x8 qf[4][2], kf[4][2];
    #pragma unroll
    for (int f = 0; f < 4; ++f) {
        const int n = TOK(f * 16 + lr);
        const bf16* pq = qkvb + (tb + n) * 768 + head * 64 + ch;
        qf[f][0] = *reinterpret_cast<const bf16x8*>(pq);
        qf[f][1] = *reinterpret_cast<const bf16x8*>(pq + 32);
        kf[f][0] = *reinterpret_cast<const bf16x8*>(pq + 256);
        kf[f][1] = *reinterpret_cast<const bf16x8*>(pq + 288);
    }

    // ---- S^T[j][q] ----
    f32x4 acc[4][4];
    #pragma unroll
    for (int fm = 0; fm < 4; ++fm)
        #pragma unroll
        for (int fn = 0; fn < 4; ++fn) {
            acc[fm][fn] = (f32x4){0.f, 0.f, 0.f, 0.f};
            acc[fm][fn] = __builtin_amdgcn_mfma_f32_16x16x32_bf16(kf[fm][0], qf[fn][0], acc[fm][fn], 0, 0, 0);
            acc[fm][fn] = __builtin_amdgcn_mfma_f32_16x16x32_bf16(kf[fm][1], qf[fn][1], acc[fm][fn], 0, 0, 0);
        }

    // ---- softmax per column q; write P^T (scaled by g/sum, bf16) to LDS ----
    const float g = 1.f / (1.f + __expf(-gate[0]));
    #pragma unroll
    for (int fn = 0; fn < 4; ++fn) {
        float mx = -3e38f;
        #pragma unroll
        for (int fm = 0; fm < 4; ++fm)
            #pragma unroll
            for (int i = 0; i < 4; ++i) {
                const int j = fm * 16 + lg * 4 + i;
                const float s = (j < 49) ? acc[fm][fn][i] * 0.125f : -3e38f;
                acc[fm][fn][i] = s;
                mx = fmaxf(mx, s);
            }
        mx = fmaxf(mx, __shfl_xor(mx, 16));
        mx = fmaxf(mx, __shfl_xor(mx, 32));
        float sum = 0.f;
        #pragma unroll
        for (int fm = 0; fm < 4; ++fm)
            #pragma unroll
            for (int i = 0; i < 4; ++i) {
                const float e = __expf(acc[fm][fn][i] - mx);
                acc[fm][fn][i] = e;
                sum += e;
            }
        sum += __shfl_xor(sum, 16);
        sum += __shfl_xor(sum, 32);
        const float ps = g / sum;
        #pragma unroll
        for (int fm = 0; fm < 4; ++fm) {
            bf16x4 st;
            #pragma unroll
            for (int i = 0; i < 4; ++i) st[i] = (bf16)(acc[fm][fn][i] * ps);
            *reinterpret_cast<bf16x4*>(&Pl[fn * 16 + lr][fm * 16 + lg * 4]) = st;
        }
    }

    // ---- zero acc for output accumulation (row switches meaning j -> d) ----
    #pragma unroll
    for (int fm = 0; fm < 4; ++fm)
        #pragma unroll
        for (int fn = 0; fn < 4; ++fn) acc[fm][fn] = (f32x4){0.f, 0.f, 0.f, 0.f};

    // ---- linear attention: den, then Q2 (elu+1, scaled by (1-g)/den) in place ----
    const float* kvm = kvbuf + (size_t)(b * NH_ + head) * 4160;
    float den[4] = {0.f, 0.f, 0.f, 0.f};
    #pragma unroll
    for (int k0 = 0; k0 < 2; ++k0)
        #pragma unroll
        for (int e = 0; e < 8; ++e) {
            const float ksv = kvm[4096 + ch + 32 * k0 + e];
            #pragma unroll
            for (int fn = 0; fn < 4; ++fn) {
                float qv = (float)qf[fn][k0][e];
                qv = qv > 0.f ? qv + 1.f : __expf(qv);   // elu(q)+1
                qf[fn][k0][e] = (bf16)qv;                 // stash q2 (unscaled)
                den[fn] += qv * ksv;
            }
        }
    #pragma unroll
    for (int fn = 0; fn < 4; ++fn) {
        den[fn] += __shfl_xor(den[fn], 16);
        den[fn] += __shfl_xor(den[fn], 32);
        const float w2 = (1.f - g) / (den[fn] + 1e-6f);
        #pragma unroll
        for (int k0 = 0; k0 < 2; ++k0)
            #pragma unroll
            for (int e = 0; e < 8; ++e)
                qf[fn][k0][e] = (bf16)((float)qf[fn][k0][e] * w2);
    }

    // ---- KVt A-frags (f32 global -> bf16), lin MFMAs ----
    #pragma unroll
    for (int fm = 0; fm < 4; ++fm)
        #pragma unroll
        for (int k0 = 0; k0 < 2; ++k0) {
            const float* pv = kvm + (fm * 16 + lr) * 64 + ch + 32 * k0;
            const f32x4 a = *reinterpret_cast<const f32x4*>(pv);
            const f32x4 c = *reinterpret_cast<const f32x4*>(pv + 4);
            bf16x8 t;
            #pragma unroll
            for (int e = 0; e < 4; ++e) { t[e] = (bf16)a[e]; t[4 + e] = (bf16)c[e]; }
            kf[fm][k0] = t;
        }
    #pragma unroll
    for (int fm = 0; fm < 4; ++fm)
        #pragma unroll
        for (int fn = 0; fn < 4; ++fn) {
            acc[fm][fn] = __builtin_amdgcn_mfma_f32_16x16x32_bf16(kf[fm][0], qf[fn][0], acc[fm][fn], 0, 0, 0);
            acc[fm][fn] = __builtin_amdgcn_mfma_f32_16x16x32_bf16(kf[fm][1], qf[fn][1], acc[fm][fn], 0, 0, 0);
        }

    // ---- Vt A-frags (gather), Pt B-frags (LDS), PV MFMAs ----
    int tj[16];
    #pragma unroll
    for (int k0 = 0; k0 < 2; ++k0)
        #pragma unroll
        for (int e = 0; e < 8; ++e) tj[k0 * 8 + e] = TOK(ch + 32 * k0 + e);
    #pragma unroll
    for (int fm = 0; fm < 4; ++fm)
        #pragma unroll
        for (int k0 = 0; k0 < 2; ++k0) {
            bf16x8 t;
            #pragma unroll
            for (int e = 0; e < 8; ++e)
                t[e] = qkvb[(tb + tj[k0 * 8 + e]) * 768 + 512 + head * 64 + fm * 16 + lr];
            kf[fm][k0] = t;
        }
    #pragma unroll
    for (int fn = 0; fn < 4; ++fn) {
        qf[fn][0] = *reinterpret_cast<const bf16x8*>(&Pl[fn * 16 + lr][ch]);
        qf[fn][1] = *reinterpret_cast<const bf16x8*>(&Pl[fn * 16 + lr][ch + 32]);
    }
    #pragma unroll
    for (int fm = 0; fm < 4; ++fm)
        #pragma unroll
        for (int fn = 0; fn < 4; ++fn) {
            acc[fm][fn] = __builtin_amdgcn_mfma_f32_16x16x32_bf16(kf[fm][0], qf[fn][0], acc[fm][fn], 0, 0, 0);
            acc[fm][fn] = __builtin_amdgcn_mfma_f32_16x16x32_bf16(kf[fm][1], qf[fn][1], acc[fm][fn], 0, 0, 0);
        }

    // ---- store: comb[token q][head*64 + d] ----
    #pragma unroll
    for (int fn = 0; fn < 4; ++fn) {
        const int q = fn * 16 + lr;
        if (q < 49) {
            const int n = TOK(q);
            bf16* po = combb + (tb + n) * CD + head * 64;
            #pragma unroll
            for (int fm = 0; fm < 4; ++fm) {
                bf16x4 st;
                #pragma unroll
                for (int i = 0; i < 4; ++i) st[i] = (bf16)acc[fm][fn][i];
                *reinterpret_cast<bf16x4*>(&po[fm * 16 + lg * 4]) = st;
            }
        }
    }
    #undef TOK
}

extern "C" void kernel_launch(void* const* d_in, const int* in_sizes, int n_in,
                              void* d_out, int out_size, void* d_ws, size_t ws_size,
                              hipStream_t stream)
{
    (void)in_sizes; (void)n_in; (void)out_size;
    const float* x     = (const float*)d_in[0];
    const float* w_in  = (const float*)d_in[1];
    const float* bn1g  = (const float*)d_in[2];
    const float* bn1b  = (const float*)d_in[3];
    const float* bn1m  = (const float*)d_in[4];
    const float* bn1v  = (const float*)d_in[5];
    const float* w_qkv = (const float*)d_in[6];
    const float* w_out = (const float*)d_in[7];
    const float* bn2g  = (const float*)d_in[8];
    const float* bn2b  = (const float*)d_in[9];
    const float* bn2m  = (const float*)d_in[10];
    const float* bn2v  = (const float*)d_in[11];
    const float* gate  = (const float*)d_in[12];
    float* out = (float*)d_out;
    char* base = (char*)d_ws;

    // Fixed region: packed weights (655360 B) + kvbuf (532480 B)
    bf16*  wb  = (bf16*)base;
    float* kvb = (float*)(base + 655360);
    char*  dyn = base + 655360 + 532480;

    const size_t xb_b  = (size_t)HW_ * CD * 2;        // 6,422,528 B per batch
    const size_t qkv_b = (size_t)HW_ * 768 * 2;       // 19,267,584 B per batch
    const size_t per_b = xb_b * 2 + qkv_b;            // xb + xpb + qkv
    size_t avail = ws_size > (size_t)(655360 + 532480) ? ws_size - 655360 - 532480 : 0;
    int nb = (int)(avail / per_b);
    if (nb < 1) nb = 1;
    if (nb > B_) nb = B_;

    bf16* xb  = (bf16*)dyn;
    bf16* xpb = (bf16*)(dyn + (size_t)nb * xb_b);     // reused as combb
    bf16* qkv = (bf16*)(dyn + (size_t)nb * xb_b * 2);

    pack_w<<<dim3(192, 3), 256, 0, stream>>>(w_in, w_qkv, w_out, wb);

    for (int b0 = 0; b0 < B_; b0 += nb) {
        const int cb = (B_ - b0) < nb ? (B_ - b0) : nb;
        const float* xc = x   + (size_t)b0 * CD * HW_;
        float*       oc = out + (size_t)b0 * CD * HW_;

        // 0) transpose+cast x -> token-major bf16
        pack_x<<<dim3(392, 8, cb), 256, 0, stream>>>(xc, xb);
        // 1) in-proj + BN1 + SiLU
        mfma_gemm<0, 256><<<dim3(2, 98, cb), 256, 0, stream>>>(
            wb, xb, xpb, nullptr, bn1g, bn1b, bn1m, bn1v, nullptr);
        // 2) qkv projection + fused RoPE
        mfma_gemm<1, 768><<<dim3(6, 98, cb), 256, 0, stream>>>(
            wb + 65536, xpb, qkv, nullptr, nullptr, nullptr, nullptr, nullptr, nullptr);
        // 3) linear attention KV^T reduction
        hipMemsetAsync(kvb, 0, (size_t)cb * NH_ * 4160 * sizeof(float), stream);
        kvred<<<dim3(16, 4, cb), 256, 0, stream>>>(qkv, kvb);
        // 4) MFMA window attention + linear attention + gate blend -> combb (reuses xpb)
        winattn_mfma<<<dim3(256, 4, cb), 64, 0, stream>>>(qkv, kvb, gate, xpb);
        // 5) out-proj + BN2 + residual
        mfma_gemm<2, 256><<<dim3(2, 98, cb), 256, 0, stream>>>(
            wb + 262144, xpb, nullptr, oc, bn2g, bn2b, bn2m, bn2v, xc);
    }
}